// Round 1
// baseline (10055.399 us; speedup 1.0000x reference)
//
#include <hip/hip_runtime.h>
#include <hip/hip_bf16.h>
#include <stdint.h>

typedef __attribute__((ext_vector_type(8))) short short8;
typedef __attribute__((ext_vector_type(4))) float f32x4;
typedef __attribute__((ext_vector_type(4))) unsigned int u32x4;

__device__ __forceinline__ unsigned short f2bf(float x) {
  unsigned int u = __builtin_bit_cast(unsigned int, x);
  u += 0x7FFFu + ((u >> 16) & 1u);           // round-to-nearest-even
  return (unsigned short)(u >> 16);
}
__device__ __forceinline__ float bf2f(unsigned short u) {
  unsigned int v = ((unsigned int)u) << 16;
  return __builtin_bit_cast(float, v);
}
__device__ __forceinline__ unsigned int pk2(float a, float b) {
  return (unsigned int)f2bf(a) | ((unsigned int)f2bf(b) << 16);
}
__device__ __forceinline__ float sigm(float x) {
  return 1.0f / (1.0f + exp2f(-1.44269504f * x));
}
__device__ __forceinline__ float tanh_(float x) {
  return 2.0f / (1.0f + exp2f(-2.88539008f * x)) - 1.0f;
}
__device__ __forceinline__ f32x4 mfma16(short8 a, short8 b, f32x4 c) {
  return __builtin_amdgcn_mfma_f32_16x16x32_bf16(a, b, c, 0, 0, 0);
}

// ---------------------------------------------------------------------------
// prep: build bf16 transposed weight images, fused bias, zero hbuf + flags.
// Gate order everywhere: 0=f, 1=i, 2=g, 3=o  (matches ref concat order).
// WxT: [2048 n][512 k]   WhT: [32 wg][64 j][512 k]  (j = gate*16 + hc_local)
// ---------------------------------------------------------------------------
__global__ void lstm_prep(
    const float* __restrict__ Wif, const float* __restrict__ Wii,
    const float* __restrict__ Wig, const float* __restrict__ Wio,
    const float* __restrict__ Whf, const float* __restrict__ Whi,
    const float* __restrict__ Whg, const float* __restrict__ Who,
    const float* __restrict__ bif, const float* __restrict__ bhf,
    const float* __restrict__ bii, const float* __restrict__ bhi,
    const float* __restrict__ big, const float* __restrict__ bhg,
    const float* __restrict__ bio, const float* __restrict__ bho,
    unsigned short* __restrict__ WxT, unsigned short* __restrict__ WhT,
    float* __restrict__ bias, unsigned short* __restrict__ hbuf,
    int* __restrict__ flags)
{
  const long NWX = 2048L * 512, NWH = 32L * 64 * 512;
  const long NH = 2L * 64 * 512;
  long total = NWX + NWH + 2048 + NH + 64;
  for (long i = (long)blockIdx.x * blockDim.x + threadIdx.x; i < total;
       i += (long)gridDim.x * blockDim.x) {
    if (i < NWX) {
      int n = (int)(i >> 9), k = (int)(i & 511);
      int g = n >> 9, hc = n & 511;
      const float* W = (g == 0) ? Wif : (g == 1) ? Wii : (g == 2) ? Wig : Wio;
      WxT[i] = f2bf(W[k * 512 + hc]);
    } else if (i < NWX + NWH) {
      long r = i - NWX;
      int wg = (int)(r >> 15); int rest = (int)(r & 32767);
      int j = rest >> 9, k = rest & 511;
      int g = j >> 4, hc = wg * 16 + (j & 15);
      const float* W = (g == 0) ? Whf : (g == 1) ? Whi : (g == 2) ? Whg : Who;
      WhT[r] = f2bf(W[k * 512 + hc]);
    } else if (i < NWX + NWH + 2048) {
      int n = (int)(i - NWX - NWH);
      int g = n >> 9, hc = n & 511;
      const float* bi = (g == 0) ? bif : (g == 1) ? bii : (g == 2) ? big : bio;
      const float* bh = (g == 0) ? bhf : (g == 1) ? bhi : (g == 2) ? bhg : bho;
      bias[n] = bi[hc] + bh[hc];
    } else if (i < NWX + NWH + 2048 + NH) {
      hbuf[i - NWX - NWH - 2048] = 0;
    } else {
      flags[i - NWX - NWH - 2048 - NH] = 0;
    }
  }
}

// ---------------------------------------------------------------------------
// x-projection GEMM: xp[t][b][n] = bf16( x[b][t][:] @ WxT[n][:] + bias[n] )
// M = 65536 (m = b*1024 + t), N = 2048, K = 512.
// 128x128 tile, BK=32, 4 waves (2x2), 16x16x32 bf16 MFMA, padded LDS.
// ---------------------------------------------------------------------------
#define GP 56  // LDS row stride (elems): 112B, 16B-aligned, 2-way banks

__global__ __launch_bounds__(256) void lstm_xproj(
    const float* __restrict__ x, const unsigned short* __restrict__ WxT,
    const float* __restrict__ bias, unsigned short* __restrict__ xp)
{
  __shared__ unsigned short As[128 * GP];
  __shared__ unsigned short Bs[128 * GP];
  int bid = blockIdx.x;
  int mt = bid & 511, nt = bid >> 9;          // 512 m-tiles, 16 n-tiles
  int m0 = mt << 7, n0 = nt << 7;
  int tid = threadIdx.x, lane = tid & 63, w = tid >> 6;
  int wm = w >> 1, wn = w & 1;
  int l15 = lane & 15, hi4 = lane >> 4;

  f32x4 acc[4][4] = {};
  int srow = tid >> 1, skq = (tid & 1) << 4;  // each thread: 1 row, 16 k
  const float* xa = x + (size_t)(m0 + srow) * 512 + skq;
  const unsigned short* bsrc = WxT + (size_t)(n0 + srow) * 512 + skq;
  unsigned short* adst = As + srow * GP + skq;
  unsigned short* bdst = Bs + srow * GP + skq;

  for (int kt = 0; kt < 16; ++kt) {
    f32x4 a0 = *(const f32x4*)(xa + kt * 32);
    f32x4 a1 = *(const f32x4*)(xa + kt * 32 + 4);
    f32x4 a2 = *(const f32x4*)(xa + kt * 32 + 8);
    f32x4 a3 = *(const f32x4*)(xa + kt * 32 + 12);
    u32x4 wv0 = *(const u32x4*)(bsrc + kt * 32);
    u32x4 wv1 = *(const u32x4*)(bsrc + kt * 32 + 8);
    u32x4 p0, p1;
    p0[0] = pk2(a0[0], a0[1]); p0[1] = pk2(a0[2], a0[3]);
    p0[2] = pk2(a1[0], a1[1]); p0[3] = pk2(a1[2], a1[3]);
    p1[0] = pk2(a2[0], a2[1]); p1[1] = pk2(a2[2], a2[3]);
    p1[2] = pk2(a3[0], a3[1]); p1[3] = pk2(a3[2], a3[3]);
    *(u32x4*)adst = p0;  *(u32x4*)(adst + 8) = p1;
    *(u32x4*)bdst = wv0; *(u32x4*)(bdst + 8) = wv1;
    __syncthreads();
    short8 af[4], bf[4];
    #pragma unroll
    for (int mb = 0; mb < 4; ++mb)
      af[mb] = *(const short8*)(As + (wm * 64 + mb * 16 + l15) * GP + hi4 * 8);
    #pragma unroll
    for (int nb = 0; nb < 4; ++nb)
      bf[nb] = *(const short8*)(Bs + (wn * 64 + nb * 16 + l15) * GP + hi4 * 8);
    #pragma unroll
    for (int mb = 0; mb < 4; ++mb)
      #pragma unroll
      for (int nb = 0; nb < 4; ++nb)
        acc[mb][nb] = mfma16(af[mb], bf[nb], acc[mb][nb]);
    __syncthreads();
  }
  // epilogue: +bias, bf16, scatter to xp[t][b][n]  (C/D: col=lane&15, row=hi*4+i)
  #pragma unroll
  for (int nb = 0; nb < 4; ++nb) {
    int n = n0 + wn * 64 + nb * 16 + l15;
    float bv = bias[n];
    #pragma unroll
    for (int mb = 0; mb < 4; ++mb) {
      int mbase = m0 + wm * 64 + mb * 16 + hi4 * 4;
      #pragma unroll
      for (int i = 0; i < 4; ++i) {
        int m = mbase + i;
        int tt = m & 1023, bb = m >> 10;
        xp[((size_t)(tt * 64 + bb)) * 2048 + n] = f2bf(acc[mb][nb][i] + bv);
      }
    }
  }
}

// ---------------------------------------------------------------------------
// recurrence: 32 persistent WGs, WG wg owns h-cols [wg*16, wg*16+16).
// Wave (wm,wn): rows 32*wm..+32 (batch), gates {f,i} (wn=0) / {g,o} (wn=1).
// Wh slice resident in LDS; per step: prefetch xp -> spin flags -> stage h ->
// 2x2 frag MFMA (K=512) -> LDS exchange of g,o -> fp32 gate update, c in regs.
// ---------------------------------------------------------------------------
#define HP 520  // LDS row stride for [64][512] bf16 tiles: 1040B, 2-way banks

__global__ __launch_bounds__(256) void lstm_rec(
    const unsigned short* __restrict__ xp, const unsigned short* __restrict__ WhT,
    unsigned short* __restrict__ hbuf, int* __restrict__ flags,
    float* __restrict__ out)
{
  __shared__ unsigned short WhS[64 * HP];   // 66.5 KB
  __shared__ unsigned short hA[64 * HP];    // 66.5 KB
  __shared__ float xch[8 * 256];            // 8 KB  (g/o exchange)

  int wg = blockIdx.x;
  int tid = threadIdx.x, lane = tid & 63, w = tid >> 6;
  int wm = w >> 1, wn = w & 1;
  int l15 = lane & 15, hi4 = lane >> 4;

  // stage Wh slice once
  const unsigned short* wsrc = WhT + (size_t)wg * 64 * 512;
  #pragma unroll
  for (int it = 0; it < 16; ++it) {
    int idx = it * 256 + tid;
    int j = idx >> 6, k8 = (idx & 63) << 3;
    *(u32x4*)(WhS + j * HP + k8) = *(const u32x4*)(wsrc + j * 512 + k8);
  }
  f32x4 creg[2] = {};
  __syncthreads();

  for (int t = 0; t < 1024; ++t) {
    // xp prefetch (independent of h; overlaps the spin)
    unsigned short xpr[2][2][4];
    const unsigned short* xpt = xp + (size_t)t * (64 * 2048);
    #pragma unroll
    for (int mb = 0; mb < 2; ++mb) {
      int b0 = wm * 32 + mb * 16 + hi4 * 4;
      #pragma unroll
      for (int nb = 0; nb < 2; ++nb) {
        int n = (wn * 2 + nb) * 512 + wg * 16 + l15;
        #pragma unroll
        for (int i = 0; i < 4; ++i)
          xpr[mb][nb][i] = xpt[(size_t)(b0 + i) * 2048 + n];
      }
    }
    // wait for all h_t slices (flag[p] >= t  <=>  p published h_t and is done
    // reading hbuf[(t-1)&1], so the double-buffer is race-free)
    if (lane < 32) {
      while (__hip_atomic_load(&flags[lane], __ATOMIC_RELAXED,
                               __HIP_MEMORY_SCOPE_AGENT) < t) {}
    }
    __threadfence();  // acquire: invalidate so we see remote h writes
    // stage h_t -> LDS (padded)
    const unsigned short* hsrc = hbuf + (size_t)(t & 1) * 32768;
    #pragma unroll
    for (int it = 0; it < 16; ++it) {
      int idx = it * 256 + tid;
      int j = idx >> 6, k8 = (idx & 63) << 3;
      *(u32x4*)(hA + j * HP + k8) = *(const u32x4*)(hsrc + j * 512 + k8);
    }
    __syncthreads();

    f32x4 acc[2][2];
    #pragma unroll
    for (int mb = 0; mb < 2; ++mb)
      #pragma unroll
      for (int nb = 0; nb < 2; ++nb)
        #pragma unroll
        for (int i = 0; i < 4; ++i)
          acc[mb][nb][i] = bf2f(xpr[mb][nb][i]);

    #pragma unroll
    for (int kk = 0; kk < 16; ++kk) {
      short8 a0 = *(const short8*)(hA + (wm * 32 + l15) * HP + kk * 32 + hi4 * 8);
      short8 a1 = *(const short8*)(hA + (wm * 32 + 16 + l15) * HP + kk * 32 + hi4 * 8);
      short8 b0 = *(const short8*)(WhS + (wn * 32 + l15) * HP + kk * 32 + hi4 * 8);
      short8 b1 = *(const short8*)(WhS + (wn * 32 + 16 + l15) * HP + kk * 32 + hi4 * 8);
      acc[0][0] = mfma16(a0, b0, acc[0][0]);
      acc[0][1] = mfma16(a0, b1, acc[0][1]);
      acc[1][0] = mfma16(a1, b0, acc[1][0]);
      acc[1][1] = mfma16(a1, b1, acc[1][1]);
    }

    if (wn == 1) {  // hand g,o tiles to the f,i waves
      #pragma unroll
      for (int mb = 0; mb < 2; ++mb) {
        *(f32x4*)(xch + ((wm * 2 + mb) * 2 + 0) * 256 + lane * 4) = acc[mb][0];
        *(f32x4*)(xch + ((wm * 2 + mb) * 2 + 1) * 256 + lane * 4) = acc[mb][1];
      }
    }
    __syncthreads();
    if (wn == 0) {
      #pragma unroll
      for (int mb = 0; mb < 2; ++mb) {
        f32x4 G = *(const f32x4*)(xch + ((wm * 2 + mb) * 2 + 0) * 256 + lane * 4);
        f32x4 O = *(const f32x4*)(xch + ((wm * 2 + mb) * 2 + 1) * 256 + lane * 4);
        int b0 = wm * 32 + mb * 16 + hi4 * 4;
        int hc = wg * 16 + l15;
        #pragma unroll
        for (int i = 0; i < 4; ++i) {
          float fg = sigm(acc[mb][0][i]);
          float ig = sigm(acc[mb][1][i]);
          float gg = tanh_(G[i]);
          float og = sigm(O[i]);
          float c = fg * creg[mb][i] + ig * gg;
          creg[mb][i] = c;
          float h = og * tanh_(c);
          if (t < 1023) {
            hbuf[(size_t)((t + 1) & 1) * 32768 + (size_t)(b0 + i) * 512 + hc] = f2bf(h);
          } else {
            out[(size_t)(b0 + i) * 512 + hc] = h;              // h output
            out[32768 + (size_t)(b0 + i) * 512 + hc] = c;      // c output
          }
        }
      }
    }
    __threadfence();   // release our h slice
    __syncthreads();
    if (tid == 0)
      __hip_atomic_store(&flags[wg], t + 1, __ATOMIC_RELEASE,
                         __HIP_MEMORY_SCOPE_AGENT);
  }
}

// ---------------------------------------------------------------------------
extern "C" void kernel_launch(void* const* d_in, const int* in_sizes, int n_in,
                              void* d_out, int out_size, void* d_ws, size_t ws_size,
                              hipStream_t stream) {
  const float* x   = (const float*)d_in[0];
  const float* Wii = (const float*)d_in[1];
  const float* Whi = (const float*)d_in[2];
  const float* Wif = (const float*)d_in[3];
  const float* Whf = (const float*)d_in[4];
  const float* Wig = (const float*)d_in[5];
  const float* Whg = (const float*)d_in[6];
  const float* Wio = (const float*)d_in[7];
  const float* Who = (const float*)d_in[8];
  const float* bii = (const float*)d_in[9];
  const float* bhi = (const float*)d_in[10];
  const float* bif = (const float*)d_in[11];
  const float* bhf = (const float*)d_in[12];
  const float* big = (const float*)d_in[13];
  const float* bhg = (const float*)d_in[14];
  const float* bio = (const float*)d_in[15];
  const float* bho = (const float*)d_in[16];

  char* ws = (char*)d_ws;
  size_t off = 0;
  auto alloc = [&](size_t bytes) {
    size_t p = off; off = (off + bytes + 255) & ~(size_t)255; return p;
  };
  unsigned short* WxT  = (unsigned short*)(ws + alloc(2048UL * 512 * 2));
  unsigned short* WhT  = (unsigned short*)(ws + alloc(32UL * 64 * 512 * 2));
  float*          bias = (float*)        (ws + alloc(2048UL * 4));
  unsigned short* hbuf = (unsigned short*)(ws + alloc(2UL * 64 * 512 * 2));
  int*            flags= (int*)          (ws + alloc(64UL * 4));
  unsigned short* xpb  = (unsigned short*)(ws + alloc(1024UL * 64 * 2048 * 2));
  if (off > ws_size) return;  // insufficient workspace -> fail visibly

  lstm_prep<<<2048, 256, 0, stream>>>(Wif, Wii, Wig, Wio, Whf, Whi, Whg, Who,
                                      bif, bhf, bii, bhi, big, bhg, bio, bho,
                                      WxT, WhT, bias, hbuf, flags);
  lstm_xproj<<<8192, 256, 0, stream>>>(x, WxT, bias, xpb);
  lstm_rec<<<32, 256, 0, stream>>>(xpb, WhT, hbuf, flags, (float*)d_out);
}

// Round 2
// 9991.365 us; speedup vs baseline: 1.0064x; 1.0064x over previous
//
#include <hip/hip_runtime.h>
#include <hip/hip_bf16.h>
#include <stdint.h>

typedef __attribute__((ext_vector_type(8))) short short8;
typedef __attribute__((ext_vector_type(4))) float f32x4;
typedef __attribute__((ext_vector_type(4))) unsigned int u32x4;

__device__ __forceinline__ unsigned short f2bf(float x) {
  unsigned int u = __builtin_bit_cast(unsigned int, x);
  u += 0x7FFFu + ((u >> 16) & 1u);           // round-to-nearest-even
  return (unsigned short)(u >> 16);
}
__device__ __forceinline__ float bf2f(unsigned short u) {
  unsigned int v = ((unsigned int)u) << 16;
  return __builtin_bit_cast(float, v);
}
__device__ __forceinline__ unsigned int pk2(float a, float b) {
  return (unsigned int)f2bf(a) | ((unsigned int)f2bf(b) << 16);
}
// fast transcendental gates (v_exp_f32 / v_rcp_f32); |preact| << 128 so safe
__device__ __forceinline__ float sigm(float x) {
  return __builtin_amdgcn_rcpf(1.0f + __builtin_amdgcn_exp2f(-1.44269504f * x));
}
__device__ __forceinline__ float tanh_(float x) {
  return 2.0f * __builtin_amdgcn_rcpf(1.0f + __builtin_amdgcn_exp2f(-2.88539008f * x)) - 1.0f;
}
__device__ __forceinline__ f32x4 mfma16(short8 a, short8 b, f32x4 c) {
  return __builtin_amdgcn_mfma_f32_16x16x32_bf16(a, b, c, 0, 0, 0);
}
__device__ __forceinline__ short8 bc(u32x4 v) { return __builtin_bit_cast(short8, v); }

// ---------------------------------------------------------------------------
// prep: bf16 transposed weight images, fused bias, zero hbuf + flags.
// Gate order everywhere: 0=f, 1=i, 2=g, 3=o (matches ref concat order).
// WxT: [2048 n][512 k]   WhT: [32 wg][64 j][512 k]  (j = gate*16 + hc_local)
// flags: 128 ushort (one per producer wave).  hbuf: 2 x [64][512] bf16.
// ---------------------------------------------------------------------------
__global__ void lstm_prep(
    const float* __restrict__ Wif, const float* __restrict__ Wii,
    const float* __restrict__ Wig, const float* __restrict__ Wio,
    const float* __restrict__ Whf, const float* __restrict__ Whi,
    const float* __restrict__ Whg, const float* __restrict__ Who,
    const float* __restrict__ bif, const float* __restrict__ bhf,
    const float* __restrict__ bii, const float* __restrict__ bhi,
    const float* __restrict__ big, const float* __restrict__ bhg,
    const float* __restrict__ bio, const float* __restrict__ bho,
    unsigned short* __restrict__ WxT, unsigned short* __restrict__ WhT,
    float* __restrict__ bias, unsigned short* __restrict__ hbuf,
    unsigned short* __restrict__ flags)
{
  const long NWX = 2048L * 512, NWH = 32L * 64 * 512;
  const long NH = 2L * 64 * 512;
  long total = NWX + NWH + 2048 + NH + 128;
  for (long i = (long)blockIdx.x * blockDim.x + threadIdx.x; i < total;
       i += (long)gridDim.x * blockDim.x) {
    if (i < NWX) {
      int n = (int)(i >> 9), k = (int)(i & 511);
      int g = n >> 9, hc = n & 511;
      const float* W = (g == 0) ? Wif : (g == 1) ? Wii : (g == 2) ? Wig : Wio;
      WxT[i] = f2bf(W[k * 512 + hc]);
    } else if (i < NWX + NWH) {
      long r = i - NWX;
      int wg = (int)(r >> 15); int rest = (int)(r & 32767);
      int j = rest >> 9, k = rest & 511;
      int g = j >> 4, hc = wg * 16 + (j & 15);
      const float* W = (g == 0) ? Whf : (g == 1) ? Whi : (g == 2) ? Whg : Who;
      WhT[r] = f2bf(W[k * 512 + hc]);
    } else if (i < NWX + NWH + 2048) {
      int n = (int)(i - NWX - NWH);
      int g = n >> 9, hc = n & 511;
      const float* bi = (g == 0) ? bif : (g == 1) ? bii : (g == 2) ? big : bio;
      const float* bh = (g == 0) ? bhf : (g == 1) ? bhi : (g == 2) ? bhg : bho;
      bias[n] = bi[hc] + bh[hc];
    } else if (i < NWX + NWH + 2048 + NH) {
      hbuf[i - NWX - NWH - 2048] = 0;
    } else {
      flags[i - NWX - NWH - 2048 - NH] = 0;
    }
  }
}

// ---------------------------------------------------------------------------
// x-projection GEMM: (B*T, 512) @ (512, 2048) + bias -> bf16, written in the
// recurrent kernel's per-lane-packed layout:
//   xp[(((t*32 + wg)*4 + w)*64 + lane)*16 + gate*4 + i]
// where (wg,w,lane,gate,i) are the consumer's coordinates.
// ---------------------------------------------------------------------------
#define GP 56  // LDS row stride (elems): 112B, 16B-aligned, 2-way banks

__global__ __launch_bounds__(256) void lstm_xproj(
    const float* __restrict__ x, const unsigned short* __restrict__ WxT,
    const float* __restrict__ bias, unsigned short* __restrict__ xp)
{
  __shared__ unsigned short As[128 * GP];
  __shared__ unsigned short Bs[128 * GP];
  int bid = blockIdx.x;
  int mt = bid & 511, nt = bid >> 9;          // 512 m-tiles, 16 n-tiles
  int m0 = mt << 7, n0 = nt << 7;
  int tid = threadIdx.x, lane = tid & 63, w = tid >> 6;
  int wm = w >> 1, wn = w & 1;
  int l15 = lane & 15, hi4 = lane >> 4;

  f32x4 acc[4][4] = {};
  int srow = tid >> 1, skq = (tid & 1) << 4;  // each thread: 1 row, 16 k
  const float* xa = x + (size_t)(m0 + srow) * 512 + skq;
  const unsigned short* bsrc = WxT + (size_t)(n0 + srow) * 512 + skq;
  unsigned short* adst = As + srow * GP + skq;
  unsigned short* bdst = Bs + srow * GP + skq;

  for (int kt = 0; kt < 16; ++kt) {
    f32x4 a0 = *(const f32x4*)(xa + kt * 32);
    f32x4 a1 = *(const f32x4*)(xa + kt * 32 + 4);
    f32x4 a2 = *(const f32x4*)(xa + kt * 32 + 8);
    f32x4 a3 = *(const f32x4*)(xa + kt * 32 + 12);
    u32x4 wv0 = *(const u32x4*)(bsrc + kt * 32);
    u32x4 wv1 = *(const u32x4*)(bsrc + kt * 32 + 8);
    u32x4 p0, p1;
    p0[0] = pk2(a0[0], a0[1]); p0[1] = pk2(a0[2], a0[3]);
    p0[2] = pk2(a1[0], a1[1]); p0[3] = pk2(a1[2], a1[3]);
    p1[0] = pk2(a2[0], a2[1]); p1[1] = pk2(a2[2], a2[3]);
    p1[2] = pk2(a3[0], a3[1]); p1[3] = pk2(a3[2], a3[3]);
    *(u32x4*)adst = p0;  *(u32x4*)(adst + 8) = p1;
    *(u32x4*)bdst = wv0; *(u32x4*)(bdst + 8) = wv1;
    __syncthreads();
    short8 af[4], bfr[4];
    #pragma unroll
    for (int mb = 0; mb < 4; ++mb)
      af[mb] = *(const short8*)(As + (wm * 64 + mb * 16 + l15) * GP + hi4 * 8);
    #pragma unroll
    for (int nb = 0; nb < 4; ++nb)
      bfr[nb] = *(const short8*)(Bs + (wn * 64 + nb * 16 + l15) * GP + hi4 * 8);
    #pragma unroll
    for (int mb = 0; mb < 4; ++mb)
      #pragma unroll
      for (int nb = 0; nb < 4; ++nb)
        acc[mb][nb] = mfma16(af[mb], bfr[nb], acc[mb][nb]);
    __syncthreads();
  }
  // epilogue: +bias, bf16, scatter into the packed consumer layout
  #pragma unroll
  for (int nb = 0; nb < 4; ++nb) {
    int n = n0 + wn * 64 + nb * 16 + l15;
    int gate = n >> 9, hc = n & 511, wgc = hc >> 4, lcol = hc & 15;
    float bv = bias[n];
    #pragma unroll
    for (int mb = 0; mb < 4; ++mb) {
      int mbase = m0 + wm * 64 + mb * 16 + hi4 * 4;
      #pragma unroll
      for (int i = 0; i < 4; ++i) {
        int m = mbase + i;
        int tt = m & 1023, bb = m >> 10;
        int wv = bb >> 4, hi = (bb >> 2) & 3, ii = bb & 3;
        size_t dst = ((((size_t)tt * 32 + wgc) * 4 + wv) * 64 +
                      (size_t)(hi * 16 + lcol)) * 16 + gate * 4 + ii;
        xp[dst] = f2bf(acc[mb][nb][i] + bv);
      }
    }
  }
}

// ---------------------------------------------------------------------------
// recurrence: 32 WGs x 4 waves. Wave (wg,w) owns batch rows [16w,16w+16) x
// h-cols [wg*16, wg*16+16) x all 4 gates. Wh b-frags live in VGPRs (256).
// Per step: xp prefetch (2 dwordx4) -> spin on 128 u16 flags (1 u32/lane) ->
// 16 asm dwordx4 sc0sc1 h loads (pipelined vmcnt(12/8/4/0)) -> 64 MFMA ->
// gate math in regs -> 4 ushort agent-atomic h stores -> vmcnt(0) -> flag.
// No LDS, no __syncthreads, no fences in the loop.
// ---------------------------------------------------------------------------
#define ALOAD(dst, OFF) \
  asm volatile("global_load_dwordx4 %0, %1, off offset:" #OFF " sc0 sc1" \
               : "=v"(dst) : "v"(haddr))
#define AWAIT(N) do { \
  asm volatile("s_waitcnt vmcnt(" #N ")" ::: "memory"); \
  __builtin_amdgcn_sched_barrier(0); } while (0)
#define MF4(K, AV) \
  acc[0] = mfma16(bc(AV), bw[0][K], acc[0]); \
  acc[1] = mfma16(bc(AV), bw[1][K], acc[1]); \
  acc[2] = mfma16(bc(AV), bw[2][K], acc[2]); \
  acc[3] = mfma16(bc(AV), bw[3][K], acc[3]);

__global__ __launch_bounds__(256, 1) void lstm_rec(
    const unsigned short* __restrict__ xp, const unsigned short* __restrict__ WhT,
    unsigned short* __restrict__ hbuf, unsigned short* __restrict__ flags,
    float* __restrict__ out)
{
  int wg = blockIdx.x;
  int tid = threadIdx.x, lane = tid & 63, w = tid >> 6;
  int l15 = lane & 15, hi4 = lane >> 4;

  // Wh b-fragments resident in registers: bw[gate][kk] (statically indexed)
  short8 bw[4][16];
  {
    const unsigned short* wsrc = WhT + (size_t)wg * 64 * 512;
    #pragma unroll
    for (int g = 0; g < 4; ++g)
      #pragma unroll
      for (int kk = 0; kk < 16; ++kk)
        bw[g][kk] = *(const short8*)(wsrc + (size_t)(g * 16 + l15) * 512 +
                                     kk * 32 + hi4 * 8);
  }

  f32x4 creg = {0.f, 0.f, 0.f, 0.f};
  const int fid = wg * 4 + w;
  const int row0 = w * 16 + hi4 * 4;     // first of this lane's 4 batch rows
  const int col = wg * 16 + l15;         // h column
  const int arow = w * 16 + l15;         // a-frag row for this lane
  const unsigned short* xpw = xp + ((size_t)(wg * 4 + w) * 64 + lane) * 16;

  for (int t = 0; t < 1024; ++t) {
    // ---- xp prefetch + acc init (independent of h; overlaps the spin) ----
    u32x4 p0 = *(const u32x4*)(xpw + (size_t)t * 131072);
    u32x4 p1 = *(const u32x4*)(xpw + (size_t)t * 131072 + 8);
    f32x4 acc[4];
    #pragma unroll
    for (int g = 0; g < 4; ++g)
      #pragma unroll
      for (int i = 0; i < 4; ++i) {
        int j = g * 4 + i;
        unsigned int dw = (j < 8) ? p0[j >> 1] : p1[(j - 8) >> 1];
        unsigned short us = (j & 1) ? (unsigned short)(dw >> 16)
                                    : (unsigned short)(dw & 0xFFFFu);
        acc[g][i] = bf2f(us);
      }
    // ---- spin: all 128 producer waves published h_t ----
    for (;;) {
      unsigned int pv = __hip_atomic_load((const unsigned int*)flags + lane,
                                          __ATOMIC_RELAXED,
                                          __HIP_MEMORY_SCOPE_AGENT);
      int ok = ((pv & 0xFFFFu) >= (unsigned)t) && ((pv >> 16) >= (unsigned)t);
      if (__all(ok)) break;
    }
    // ---- a-frags: 16B cache-bypass loads straight from hbuf ----
    unsigned long long haddr = (unsigned long long)(uintptr_t)(
        hbuf + (((size_t)t & 1) << 15) + (size_t)arow * 512 + hi4 * 8);
    u32x4 av0, av1, av2, av3, av4, av5, av6, av7;
    u32x4 av8, av9, av10, av11, av12, av13, av14, av15;
    ALOAD(av0, 0);    ALOAD(av1, 64);   ALOAD(av2, 128);  ALOAD(av3, 192);
    ALOAD(av4, 256);  ALOAD(av5, 320);  ALOAD(av6, 384);  ALOAD(av7, 448);
    ALOAD(av8, 512);  ALOAD(av9, 576);  ALOAD(av10, 640); ALOAD(av11, 704);
    ALOAD(av12, 768); ALOAD(av13, 832); ALOAD(av14, 896); ALOAD(av15, 960);
    AWAIT(12);
    MF4(0, av0)  MF4(1, av1)  MF4(2, av2)  MF4(3, av3)
    AWAIT(8);
    MF4(4, av4)  MF4(5, av5)  MF4(6, av6)  MF4(7, av7)
    AWAIT(4);
    MF4(8, av8)  MF4(9, av9)  MF4(10, av10) MF4(11, av11)
    AWAIT(0);
    MF4(12, av12) MF4(13, av13) MF4(14, av14) MF4(15, av15)
    // ---- gates (all local to the lane) ----
    float hv[4];
    #pragma unroll
    for (int i = 0; i < 4; ++i) {
      float fg = sigm(acc[0][i]);
      float ig = sigm(acc[1][i]);
      float gg = tanh_(acc[2][i]);
      float og = sigm(acc[3][i]);
      float c = fg * creg[i] + ig * gg;
      creg[i] = c;
      hv[i] = og * tanh_(c);
    }
    if (t < 1023) {
      // publish h_{t+1}: write-through atomics, drain, then flag
      unsigned short* hb = hbuf + (((size_t)(t + 1) & 1) << 15);
      #pragma unroll
      for (int i = 0; i < 4; ++i)
        __hip_atomic_store(hb + (size_t)(row0 + i) * 512 + col, f2bf(hv[i]),
                           __ATOMIC_RELAXED, __HIP_MEMORY_SCOPE_AGENT);
      asm volatile("s_waitcnt vmcnt(0)" ::: "memory");
      if (lane == 0)
        __hip_atomic_store(flags + fid, (unsigned short)(t + 1),
                           __ATOMIC_RELAXED, __HIP_MEMORY_SCOPE_AGENT);
    } else {
      #pragma unroll
      for (int i = 0; i < 4; ++i) {
        out[(size_t)(row0 + i) * 512 + col] = hv[i];            // h (fp32)
        out[32768 + (size_t)(row0 + i) * 512 + col] = creg[i];  // c (fp32)
      }
    }
  }
}

// ---------------------------------------------------------------------------
extern "C" void kernel_launch(void* const* d_in, const int* in_sizes, int n_in,
                              void* d_out, int out_size, void* d_ws, size_t ws_size,
                              hipStream_t stream) {
  const float* x   = (const float*)d_in[0];
  const float* Wii = (const float*)d_in[1];
  const float* Whi = (const float*)d_in[2];
  const float* Wif = (const float*)d_in[3];
  const float* Whf = (const float*)d_in[4];
  const float* Wig = (const float*)d_in[5];
  const float* Whg = (const float*)d_in[6];
  const float* Wio = (const float*)d_in[7];
  const float* Who = (const float*)d_in[8];
  const float* bii = (const float*)d_in[9];
  const float* bhi = (const float*)d_in[10];
  const float* bif = (const float*)d_in[11];
  const float* bhf = (const float*)d_in[12];
  const float* big = (const float*)d_in[13];
  const float* bhg = (const float*)d_in[14];
  const float* bio = (const float*)d_in[15];
  const float* bho = (const float*)d_in[16];

  char* ws = (char*)d_ws;
  size_t off = 0;
  auto alloc = [&](size_t bytes) {
    size_t p = off; off = (off + bytes + 255) & ~(size_t)255; return p;
  };
  unsigned short* WxT  = (unsigned short*)(ws + alloc(2048UL * 512 * 2));
  unsigned short* WhT  = (unsigned short*)(ws + alloc(32UL * 64 * 512 * 2));
  float*          bias = (float*)        (ws + alloc(2048UL * 4));
  unsigned short* hbuf = (unsigned short*)(ws + alloc(2UL * 64 * 512 * 2));
  unsigned short* flags= (unsigned short*)(ws + alloc(128UL * 2));
  unsigned short* xpb  = (unsigned short*)(ws + alloc(1024UL * 64 * 2048 * 2));
  if (off > ws_size) return;  // insufficient workspace -> fail visibly

  lstm_prep<<<2048, 256, 0, stream>>>(Wif, Wii, Wig, Wio, Whf, Whi, Whg, Who,
                                      bif, bhf, bii, bhi, big, bhg, bio, bho,
                                      WxT, WhT, bias, hbuf, flags);
  lstm_xproj<<<8192, 256, 0, stream>>>(x, WxT, bias, xpb);
  lstm_rec<<<32, 256, 0, stream>>>(xpb, WhT, hbuf, flags, (float*)d_out);
}